// Round 13
// baseline (397.998 us; speedup 1.0000x reference)
//
#include <hip/hip_runtime.h>

typedef unsigned short u16;
typedef unsigned int   u32;
typedef __attribute__((ext_vector_type(8))) short bf16x8;
typedef __attribute__((ext_vector_type(4))) float f32x4;

__device__ __forceinline__ u16 f2bf(float f){
  u32 u = __builtin_bit_cast(u32, f);
  u32 r = (u + 0x7FFFu + ((u >> 16) & 1u)) >> 16;
  return (u16)r;
}
__device__ __forceinline__ float bf2f(u16 h){
  u32 u = ((u32)h) << 16;
  return __builtin_bit_cast(float, u);
}
__device__ __forceinline__ void llds16(const u16* g, u16* l){
  __builtin_amdgcn_global_load_lds((const __attribute__((address_space(1))) void*)g,
                                   (__attribute__((address_space(3))) void*)l, 16, 0, 0);
}

// ---------------- fused casts: x (2.1M f4) | w1 pad (4.3M f4) | w2 (2.1M f4) ----------------
__global__ __launch_bounds__(256)
void castall(const float* __restrict__ x, const float* __restrict__ w1, const float* __restrict__ w2,
             u16* __restrict__ x_bf, u16* __restrict__ w1p, u16* __restrict__ w2b)
{
  int i = blockIdx.x * 256 + threadIdx.x;    // over 8,519,680 float4
  float4 v;
  uint2* dst;
  if (i < 2097152) {
    v = ((const float4*)x)[i];
    dst = (uint2*)x_bf + i;
  } else if (i < 2097152 + 4325376) {
    int j = i - 2097152;                     // float4 index over 8448*512
    int nrow = j >> 9;
    v = make_float4(0.f, 0.f, 0.f, 0.f);
    if (nrow < 8384) v = ((const float4*)w1)[j];
    dst = (uint2*)w1p + j;
  } else {
    int j = i - 6422528;
    v = ((const float4*)w2)[j];
    dst = (uint2*)w2b + j;
  }
  u32 lo = (u32)f2bf(v.x) | ((u32)f2bf(v.y) << 16);
  u32 hi = (u32)f2bf(v.z) | ((u32)f2bf(v.w) << 16);
  *dst = make_uint2(lo, hi);
}

// ---------------- 128x128 BK=64 GEMM for GEMM1 (m97 structure + subtile swizzle) ----------------
// Grid 2112 = 32 ty x 66 tx. 2D XCD chunk: 8 XCDs = 4 ty-groups(8) x 2 tx-groups(33).
__global__ __launch_bounds__(256)
void gemm128(const u16* __restrict__ A, const u16* __restrict__ Bm, u16* __restrict__ Cout,
             int N, int K)
{
  __shared__ u16 As[8192], Bs[8192];
  const int tid = threadIdx.x;
  const int lane = tid & 63, wave = tid >> 6;
  const int wm = (wave >> 1) * 64, wn = (wave & 1) * 64;
  const int lr = lane & 15, lk8 = (lane >> 4) * 8;
  const int lterm = lr * 32 + (lk8 ^ ((lr & 8) << 1));   // swizzled read offset within subtile
  const int lid = blockIdx.x;
  const int xcd = lid & 7, w = lid >> 3;                  // w in [0,264)
  const int ty = (xcd & 3) * 8 + (w & 7);                 // 4 ty-groups of 8
  const int tx = (xcd >> 2) * 33 + (w >> 3);              // 2 tx-groups of 33
  const size_t bm0 = (size_t)ty * 128;
  const size_t bn0 = (size_t)tx * 128;
  const int cg = (lane & 3) ^ ((lane & 32) ? 2 : 0);      // inverse swizzle on k-chunk
  const int rsub = lane >> 2;
  const int ag0 = (wave >> 1) * 8;
  const int bg0 = (wave & 1) * 8;

  f32x4 acc[4][4] = {};

  for (int k0 = 0; k0 < K; k0 += 64) {
    __syncthreads();                                      // prev-tile reads complete (WAR)
    #pragma unroll
    for (int u = 0; u < 4; u++) {
      const int si = wave * 4 + u;                        // subtile 0..15 across 4 waves
      const int row = (si >> 1) * 16 + rsub;
      const int kc = (si & 1) * 32 + cg * 8;
      llds16(A  + (bm0 + row) * (size_t)K + k0 + kc, As + si * 512 + lane * 8);
      llds16(Bm + (bn0 + row) * (size_t)K + k0 + kc, Bs + si * 512 + lane * 8);
    }
    __syncthreads();                                      // drains vmcnt: tile resident
    #pragma unroll
    for (int kb = 0; kb < 2; kb++) {
      bf16x8 af[4], bfv[4];
      #pragma unroll
      for (int m = 0; m < 4; m++) af[m]  = *(const bf16x8*)&As[(ag0 + m * 2 + kb) * 512 + lterm];
      #pragma unroll
      for (int n = 0; n < 4; n++) bfv[n] = *(const bf16x8*)&Bs[(bg0 + n * 2 + kb) * 512 + lterm];
      #pragma unroll
      for (int m = 0; m < 4; m++)
        #pragma unroll
        for (int n = 0; n < 4; n++)
          acc[m][n] = __builtin_amdgcn_mfma_f32_16x16x32_bf16(af[m], bfv[n], acc[m][n], 0, 0, 0);
    }
  }

  const int lg = (lane >> 4) * 4;
  #pragma unroll
  for (int m = 0; m < 4; m++)
    #pragma unroll
    for (int n = 0; n < 4; n++) {
      size_t col = bn0 + wn + n * 16 + lr;
      #pragma unroll
      for (int j = 0; j < 4; j++) {
        size_t row = bm0 + wm + m * 16 + lg + j;
        Cout[row * N + col] = f2bf(acc[m][n][j]);
      }
    }
}

// ---------------- split-K=2 on the gemm128 structure (GEMM2): grid 1024, 2D XCD chunk ----------------
// ks = lid>>9; within-slice 512 tiles (32 ty x 16 tx); 8 XCDs = 4 ty-groups(8) x 2 tx-groups(8),
// ty fast -> per-XCD A-panel 4.2 MB L2-resident, B tile 0.5 MB hot. Per-WG K=2048, LDK=4096.
__global__ __launch_bounds__(256)
void gemm128sk(const u16* __restrict__ A, const u16* __restrict__ Bm, float* __restrict__ P,
               int N, int KLEN, int LDK)
{
  __shared__ u16 As[8192], Bs[8192];
  const int tid = threadIdx.x;
  const int lane = tid & 63, wave = tid >> 6;
  const int wm = (wave >> 1) * 64, wn = (wave & 1) * 64;
  const int lr = lane & 15, lk8 = (lane >> 4) * 8;
  const int lterm = lr * 32 + (lk8 ^ ((lr & 8) << 1));
  const int lid = blockIdx.x;
  const int ks = lid >> 9;                                // k-slice 0/1
  const int lid2 = lid & 511;
  const int xcd = lid2 & 7, w = lid2 >> 3;                // w in [0,64)
  const int ty = (xcd & 3) * 8 + (w & 7);                 // [0,32)
  const int tx = (xcd >> 2) * 8 + (w >> 3);               // [0,16)
  const size_t bm0 = (size_t)ty * 128;
  const size_t bn0 = (size_t)tx * 128;
  const size_t koff = (size_t)ks * KLEN;
  float* Pout = P + (size_t)ks * 8388608;                 // 4096*2048
  const int cg = (lane & 3) ^ ((lane & 32) ? 2 : 0);
  const int rsub = lane >> 2;
  const int ag0 = (wave >> 1) * 8;
  const int bg0 = (wave & 1) * 8;

  f32x4 acc[4][4] = {};

  for (int k0 = 0; k0 < KLEN; k0 += 64) {
    __syncthreads();
    #pragma unroll
    for (int u = 0; u < 4; u++) {
      const int si = wave * 4 + u;
      const int row = (si >> 1) * 16 + rsub;
      const int kc = (si & 1) * 32 + cg * 8;
      llds16(A  + (bm0 + row) * (size_t)LDK + koff + k0 + kc, As + si * 512 + lane * 8);
      llds16(Bm + (bn0 + row) * (size_t)LDK + koff + k0 + kc, Bs + si * 512 + lane * 8);
    }
    __syncthreads();
    #pragma unroll
    for (int kb = 0; kb < 2; kb++) {
      bf16x8 af[4], bfv[4];
      #pragma unroll
      for (int m = 0; m < 4; m++) af[m]  = *(const bf16x8*)&As[(ag0 + m * 2 + kb) * 512 + lterm];
      #pragma unroll
      for (int n = 0; n < 4; n++) bfv[n] = *(const bf16x8*)&Bs[(bg0 + n * 2 + kb) * 512 + lterm];
      #pragma unroll
      for (int m = 0; m < 4; m++)
        #pragma unroll
        for (int n = 0; n < 4; n++)
          acc[m][n] = __builtin_amdgcn_mfma_f32_16x16x32_bf16(af[m], bfv[n], acc[m][n], 0, 0, 0);
    }
  }

  const int lg = (lane >> 4) * 4;
  #pragma unroll
  for (int m = 0; m < 4; m++)
    #pragma unroll
    for (int n = 0; n < 4; n++) {
      size_t col = bn0 + wn + n * 16 + lr;
      #pragma unroll
      for (int j = 0; j < 4; j++) {
        size_t row = bm0 + wm + m * 16 + lg + j;
        Pout[row * N + col] = acc[m][n][j];
      }
    }
}

// ---------------- partial add: out = p0 + p1 (f32, float4) ----------------
__global__ __launch_bounds__(256)
void addp(const float* __restrict__ p0, const float* __restrict__ p1, float* __restrict__ out){
  int i = blockIdx.x * 256 + threadIdx.x;   // over 2097152 float4
  float4 a = ((const float4*)p0)[i];
  float4 b = ((const float4*)p1)[i];
  ((float4*)out)[i] = make_float4(a.x + b.x, a.y + b.y, a.z + b.z, a.w + b.w);
}

// ---------------- postproj: dt_f, B, C ----------------
__global__ __launch_bounds__(256)
void postproj(const u16* __restrict__ proj, const float* __restrict__ dt_bias,
              float* __restrict__ dtf, u16* __restrict__ Bb, u16* __restrict__ Cb)
{
  int i = blockIdx.x * 256 + threadIdx.x;     // over 4096*64
  if (i >= 4096 * 64) return;
  int bl = i >> 6, hh = i & 63;
  const u16* pr = proj + (size_t)bl * 8448;
  float dv = bf2f(pr[8320 + hh]) + dt_bias[hh];
  dtf[i] = dv > 20.f ? dv : log1pf(__expf(dv));
  Bb[i] = pr[8192 + hh];
  Cb[i] = pr[8256 + hh];
}

// ---------------- conv + silu: writes ONLY xact ----------------
__global__ __launch_bounds__(256)
void conv_silu(const u16* __restrict__ proj, const float* __restrict__ cw,
               const float* __restrict__ cb, u16* __restrict__ xact)
{
  const int g = blockIdx.x;                  // 0..1023, 4 consecutive bl each (batch-aligned)
  const int bl0 = g * 4;
  const int l0 = bl0 & 2047;
  const int d0 = blockIdx.y * 2048 + threadIdx.x * 8;
  float4 wv[8];
  #pragma unroll
  for (int e = 0; e < 8; e++) wv[e] = *(const float4*)&cw[(size_t)(d0 + e) * 4];
  float bias[8];
  {
    float4 b0 = *(const float4*)&cb[d0];
    float4 b1 = *(const float4*)&cb[d0 + 4];
    bias[0]=b0.x; bias[1]=b0.y; bias[2]=b0.z; bias[3]=b0.w;
    bias[4]=b1.x; bias[5]=b1.y; bias[6]=b1.z; bias[7]=b1.w;
  }
  float r[7][8];
  #pragma unroll
  for (int t = 0; t < 7; t++) {
    const int l = l0 - 3 + t;
    if (l >= 0) {
      uint4 rv = *(const uint4*)(proj + (size_t)(bl0 - 3 + t) * 8448 + d0);
      const u16* re = (const u16*)&rv;
      #pragma unroll
      for (int e = 0; e < 8; e++) r[t][e] = bf2f(re[e]);
    } else {
      #pragma unroll
      for (int e = 0; e < 8; e++) r[t][e] = 0.f;
    }
  }
  #pragma unroll
  for (int lo = 0; lo < 4; lo++) {
    u16 xo[8];
    #pragma unroll
    for (int e = 0; e < 8; e++) {
      float v = bias[e] + wv[e].x * r[lo][e] + wv[e].y * r[lo + 1][e]
                        + wv[e].z * r[lo + 2][e] + wv[e].w * r[lo + 3][e];
      float sil = v / (1.f + __expf(-v));
      xo[e]  = f2bf(sil);
    }
    *(uint4*)(xact + (size_t)(bl0 + lo) * 4096 + d0) = *(const uint4*)xo;
  }
}

// ---------------- SSD pass 1: per-(b,c,h) chunk states -> Stg (bf16), dtot ----------------
__global__ __launch_bounds__(256)
void ssd_states(const u16* __restrict__ xg, const u16* __restrict__ Bg,
                const float* __restrict__ dtf, const float* __restrict__ A_log,
                u16* __restrict__ Stg, float* __restrict__ dtot)
{
  const int wg = blockIdx.x;                 // b*2048 + c*64 + h
  const int b = wg >> 11, h = wg & 63;
  const int c = (wg >> 6) & 31;
  const int bl0 = b * 2048 + c * 64;
  __shared__ u16 Bt[64*64], Xts[64*64];
  __shared__ float avals[64], Acum[64], Adec[64];
  const int tid = threadIdx.x, wave = tid >> 6, lane = tid & 63;
  const int qi = (wave >> 1) * 32, qj = (wave & 1) * 32;
  const int lr = lane & 15, lk8 = (lane >> 4) * 8, lg = (lane >> 4) * 4;
  const float negA = -__expf(A_log[h]);

  if (tid < 64) avals[tid] = negA * dtf[(size_t)(bl0 + tid) * 64 + h];
  __syncthreads();
  if (tid < 64) { float s = 0.f; for (int j = 0; j <= tid; j++) s += avals[j]; Acum[tid] = s; }
  __syncthreads();
  if (tid < 64) Adec[tid] = __expf(Acum[63] - Acum[tid]);
  if (tid == 0) dtot[wg] = __expf(Acum[63]);
  __syncthreads();
  {
    int s = tid & 63, c0 = (tid >> 6) * 16;
    float f = dtf[(size_t)(bl0 + s) * 64 + h] * Adec[s];
    const u16* bs = Bg + (size_t)(bl0 + s) * 64 + c0;
    const u16* xs = xg + (size_t)(bl0 + s) * 4096 + h * 64 + c0;
    #pragma unroll
    for (int j = 0; j < 16; j++) {
      Bt[(c0 + j) * 64 + s] = bs[j];
      Xts[(c0 + j) * 64 + s] = f2bf(bf2f(xs[j]) * f);
    }
  }
  __syncthreads();
  f32x4 accst[2][2] = {};
  #pragma unroll
  for (int kk = 0; kk < 64; kk += 32) {
    bf16x8 xsf[2], btf[2];
    #pragma unroll
    for (int t = 0; t < 2; t++) {
      xsf[t] = *(const bf16x8*)&Xts[(qi + t * 16 + lr) * 64 + kk + lk8];
      btf[t] = *(const bf16x8*)&Bt [(qj + t * 16 + lr) * 64 + kk + lk8];
    }
    #pragma unroll
    for (int ti = 0; ti < 2; ti++)
      #pragma unroll
      for (int tj = 0; tj < 2; tj++)
        accst[ti][tj] = __builtin_amdgcn_mfma_f32_16x16x32_bf16(xsf[ti], btf[tj], accst[ti][tj], 0, 0, 0);
  }
  u16* So = Stg + (size_t)wg * 4096;
  #pragma unroll
  for (int ti = 0; ti < 2; ti++)
    #pragma unroll
    for (int tj = 0; tj < 2; tj++) {
      int nn = qj + tj * 16 + lr;
      #pragma unroll
      for (int r2 = 0; r2 < 4; r2++) {
        int pp = qi + ti * 16 + lg + r2;
        So[pp * 64 + nn] = f2bf(accst[ti][tj][r2]);
      }
    }
}

// ---------------- SSD pass 2: in-place scan over chunks ----------------
__global__ __launch_bounds__(256)
void ssd_scan(u16* __restrict__ Stg, const float* __restrict__ dtot)
{
  const int gid = blockIdx.x * 256 + threadIdx.x;  // 524288 threads
  const int bh = gid >> 12;                        // (b,h): 0..127
  const int pn = gid & 4095;
  const int b = bh >> 6, h = bh & 63;
  float R = 0.f;
  for (int c = 0; c < 32; ++c) {
    const int whc = b * 2048 + c * 64 + h;
    size_t idx = (size_t)whc * 4096 + pn;
    float st = bf2f(Stg[idx]);
    Stg[idx] = f2bf(R);                            // S_prev for chunk c
    R = R * dtot[whc] + st;
  }
}

// ---------------- SSD pass 3: per-(b,c,h) Y = Ydiag + Yoff, epilogue ----------------
__global__ __launch_bounds__(256)
void ssd_y(const u16* __restrict__ xg, const u16* __restrict__ Bg, const u16* __restrict__ Cg,
           const float* __restrict__ dtf, const float* __restrict__ A_log,
           const u16* __restrict__ proj, const float* __restrict__ Dskip,
           const u16* __restrict__ Stg, u16* __restrict__ Yout)
{
  const int wg = blockIdx.x;
  const int b = wg >> 11, h = wg & 63;
  const int c = (wg >> 6) & 31;
  const int bl0 = b * 2048 + c * 64;
  __shared__ u16 Cb[64*64], Bb[64*64], Xt[64*64], Sb[64*64], P[64*64];
  __shared__ float avals[64], Acum[64], Aexp[64];
  const int tid = threadIdx.x, wave = tid >> 6, lane = tid & 63;
  const int qi = (wave >> 1) * 32, qj = (wave & 1) * 32;
  const int lr = lane & 15, lk8 = (lane >> 4) * 8, lg = (lane >> 4) * 4;
  const float negA = -__expf(A_log[h]);

  if (tid < 64) avals[tid] = negA * dtf[(size_t)(bl0 + tid) * 64 + h];
  __syncthreads();
  if (tid < 64) { float s = 0.f; for (int j = 0; j <= tid; j++) s += avals[j]; Acum[tid] = s; }
  __syncthreads();
  if (tid < 64) Aexp[tid] = __expf(Acum[tid]);
  __syncthreads();
  {
    int l = tid >> 2, n0 = (tid & 3) * 16;
    const uint4* s0 = (const uint4*)(Cg + (size_t)(bl0 + l) * 64 + n0);
    *(uint4*)&Cb[l * 64 + n0] = s0[0]; *(uint4*)&Cb[l * 64 + n0 + 8] = s0[1];
    const uint4* s1 = (const uint4*)(Bg + (size_t)(bl0 + l) * 64 + n0);
    *(uint4*)&Bb[l * 64 + n0] = s1[0]; *(uint4*)&Bb[l * 64 + n0 + 8] = s1[1];
    int s = tid & 63, c0 = (tid >> 6) * 16;
    float dts = dtf[(size_t)(bl0 + s) * 64 + h];
    const u16* xs = xg + (size_t)(bl0 + s) * 4096 + h * 64 + c0;
    #pragma unroll
    for (int j = 0; j < 16; j++) Xt[(c0 + j) * 64 + s] = f2bf(bf2f(xs[j]) * dts);
    const uint4* sp = (const uint4*)(Stg + (size_t)wg * 4096 + tid * 16);
    *(uint4*)&Sb[tid * 16] = sp[0]; *(uint4*)&Sb[tid * 16 + 8] = sp[1];
  }
  __syncthreads();
  f32x4 accs[2][2] = {}; f32x4 accy[2][2] = {};
  #pragma unroll
  for (int kk = 0; kk < 64; kk += 32) {
    bf16x8 cf[2], bfr[2], sf[2];
    #pragma unroll
    for (int t = 0; t < 2; t++) {
      cf[t]  = *(const bf16x8*)&Cb[(qi + t * 16 + lr) * 64 + kk + lk8];
      bfr[t] = *(const bf16x8*)&Bb[(qj + t * 16 + lr) * 64 + kk + lk8];
      sf[t]  = *(const bf16x8*)&Sb[(qj + t * 16 + lr) * 64 + kk + lk8];
    }
    #pragma unroll
    for (int ti = 0; ti < 2; ti++)
      #pragma unroll
      for (int tj = 0; tj < 2; tj++) {
        accs[ti][tj] = __builtin_amdgcn_mfma_f32_16x16x32_bf16(cf[ti], bfr[tj], accs[ti][tj], 0, 0, 0);
        accy[ti][tj] = __builtin_amdgcn_mfma_f32_16x16x32_bf16(cf[ti], sf[tj],  accy[ti][tj], 0, 0, 0);
      }
  }
  #pragma unroll
  for (int ti = 0; ti < 2; ti++)
    #pragma unroll
    for (int tj = 0; tj < 2; tj++) {
      int j = qj + tj * 16 + lr;
      float Aj = Acum[j];
      #pragma unroll
      for (int r2 = 0; r2 < 4; r2++) {
        int i = qi + ti * 16 + lg + r2;
        float v = (i >= j) ? accs[ti][tj][r2] * __expf(Acum[i] - Aj) : 0.f;
        P[i * 64 + j] = f2bf(v);
        accy[ti][tj][r2] *= Aexp[i];
      }
    }
  __syncthreads();
  #pragma unroll
  for (int kk = 0; kk < 64; kk += 32) {
    bf16x8 pf[2], xf_[2];
    #pragma unroll
    for (int t = 0; t < 2; t++) {
      pf[t]  = *(const bf16x8*)&P [(qi + t * 16 + lr) * 64 + kk + lk8];
      xf_[t] = *(const bf16x8*)&Xt[(qj + t * 16 + lr) * 64 + kk + lk8];
    }
    #pragma unroll
    for (int ti = 0; ti < 2; ti++)
      #pragma unroll
      for (int tj = 0; tj < 2; tj++)
        accy[ti][tj] = __builtin_amdgcn_mfma_f32_16x16x32_bf16(pf[ti], xf_[tj], accy[ti][tj], 0, 0, 0);
  }
  #pragma unroll
  for (int ti = 0; ti < 2; ti++)
    #pragma unroll
    for (int tj = 0; tj < 2; tj++) {
      int pcol = qj + tj * 16 + lr;
      int d = h * 64 + pcol;
      float dsk = Dskip[d];
      #pragma unroll
      for (int r2 = 0; r2 < 4; r2++) {
        int lrow = qi + ti * 16 + lg + r2;
        size_t bl = (size_t)bl0 + lrow;
        float y = accy[ti][tj][r2];
        float xa = bf2f(xg[bl * 4096 + d]);
        float z = bf2f(proj[bl * 8448 + 4096 + d]);
        float sz = z / (1.f + __expf(-z));
        Yout[bl * 4096 + d] = f2bf((y + dsk * xa) * sz);
      }
    }
}

// ---------------- SSD fallback: one WG per (b,h), sequential ----------------
__global__ __launch_bounds__(256)
void ssd_kernel(const u16* __restrict__ xg, const u16* __restrict__ Bg, const u16* __restrict__ Cg,
                const float* __restrict__ dtf, const float* __restrict__ A_log,
                const u16* __restrict__ proj, const float* __restrict__ Dskip,
                u16* __restrict__ Yout)
{
  const int bh = blockIdx.x;
  const int b = bh >> 6, h = bh & 63;
  __shared__ float S[64 * 64];
  __shared__ u16 Cb[64*64], Bb[64*64], Bt[64*64], Xt[64*64], Xts[64*64], Sb[64*64], P[64*64];
  __shared__ float avals[64], Acum[64], Adec[64], Aexp[64];
  const int tid = threadIdx.x, wave = tid >> 6, lane = tid & 63;
  const int qi = (wave >> 1) * 32, qj = (wave & 1) * 32;
  const int lr = lane & 15, lk8 = (lane >> 4) * 8, lg = (lane >> 4) * 4;
  const float negA = -__expf(A_log[h]);

  for (int i = tid; i < 4096; i += 256) S[i] = 0.f;

  for (int c = 0; c < 32; ++c) {
    const int bl0 = b * 2048 + c * 64;
    __syncthreads();
    if (tid < 64) avals[tid] = negA * dtf[(size_t)(bl0 + tid) * 64 + h];
    __syncthreads();
    if (tid < 64) { float s = 0.f; for (int j = 0; j <= tid; j++) s += avals[j]; Acum[tid] = s; }
    __syncthreads();
    if (tid < 64) { float At = Acum[63]; Adec[tid] = __expf(At - Acum[tid]); Aexp[tid] = __expf(Acum[tid]); }
    __syncthreads();
    {
      int l = tid >> 2, n0 = (tid & 3) * 16;
      const uint4* s0 = (const uint4*)(Cg + (size_t)(bl0 + l) * 64 + n0);
      *(uint4*)&Cb[l * 64 + n0] = s0[0]; *(uint4*)&Cb[l * 64 + n0 + 8] = s0[1];
      const uint4* s1 = (const uint4*)(Bg + (size_t)(bl0 + l) * 64 + n0);
      *(uint4*)&Bb[l * 64 + n0] = s1[0]; *(uint4*)&Bb[l * 64 + n0 + 8] = s1[1];
      int s = tid & 63, c0 = (tid >> 6) * 16;
      float dec = Adec[s];
      float dts = dtf[(size_t)(bl0 + s) * 64 + h];
      const u16* bs = Bg + (size_t)(bl0 + s) * 64 + c0;
      const u16* xs = xg + (size_t)(bl0 + s) * 4096 + h * 64 + c0;
      #pragma unroll
      for (int j = 0; j < 16; j++) {
        Bt[(c0 + j) * 64 + s] = bs[j];
        float xv = bf2f(xs[j]) * dts;
        Xt[(c0 + j) * 64 + s] = f2bf(xv);
        Xts[(c0 + j) * 64 + s] = f2bf(xv * dec);
      }
      int p = tid >> 2, m0 = (tid & 3) * 16;
      #pragma unroll
      for (int j = 0; j < 16; j++) Sb[p * 64 + m0 + j] = f2bf(S[p * 64 + m0 + j]);
    }
    __syncthreads();
    f32x4 accs[2][2] = {}; f32x4 accy[2][2] = {};
    #pragma unroll
    for (int kk = 0; kk < 64; kk += 32) {
      bf16x8 cf[2], bfr[2], sf[2];
      #pragma unroll
      for (int t = 0; t < 2; t++) {
        cf[t]  = *(const bf16x8*)&Cb[(qi + t * 16 + lr) * 64 + kk + lk8];
        bfr[t] = *(const bf16x8*)&Bb[(qj + t * 16 + lr) * 64 + kk + lk8];
        sf[t]  = *(const bf16x8*)&Sb[(qj + t * 16 + lr) * 64 + kk + lk8];
      }
      #pragma unroll
      for (int ti = 0; ti < 2; ti++)
        #pragma unroll
        for (int tj = 0; tj < 2; tj++) {
          accs[ti][tj] = __builtin_amdgcn_mfma_f32_16x16x32_bf16(cf[ti], bfr[tj], accs[ti][tj], 0, 0, 0);
          accy[ti][tj] = __builtin_amdgcn_mfma_f32_16x16x32_bf16(cf[ti], sf[tj],  accy[ti][tj], 0, 0, 0);
        }
    }
    #pragma unroll
    for (int ti = 0; ti < 2; ti++)
      #pragma unroll
      for (int tj = 0; tj < 2; tj++) {
        int j = qj + tj * 16 + lr;
        float Aj = Acum[j];
        #pragma unroll
        for (int r2 = 0; r2 < 4; r2++) {
          int i = qi + ti * 16 + lg + r2;
          float v = (i >= j) ? accs[ti][tj][r2] * __expf(Acum[i] - Aj) : 0.f;
          P[i * 64 + j] = f2bf(v);
          accy[ti][tj][r2] *= Aexp[i];
        }
      }
    __syncthreads();
    f32x4 accst[2][2] = {};
    #pragma unroll
    for (int kk = 0; kk < 64; kk += 32) {
      bf16x8 pf[2], xf_[2], xsf[2], btf[2];
      #pragma unroll
      for (int t = 0; t < 2; t++) {
        pf[t]  = *(const bf16x8*)&P  [(qi + t * 16 + lr) * 64 + kk + lk8];
        xf_[t] = *(const bf16x8*)&Xt [(qj + t * 16 + lr) * 64 + kk + lk8];
        xsf[t] = *(const bf16x8*)&Xts[(qi + t * 16 + lr) * 64 + kk + lk8];
        btf[t] = *(const bf16x8*)&Bt [(qj + t * 16 + lr) * 64 + kk + lk8];
      }
      #pragma unroll
      for (int ti = 0; ti < 2; ti++)
        #pragma unroll
        for (int tj = 0; tj < 2; tj++) {
          accy[ti][tj]  = __builtin_amdgcn_mfma_f32_16x16x32_bf16(pf[ti],  xf_[tj], accy[ti][tj],  0, 0, 0);
          accst[ti][tj] = __builtin_amdgcn_mfma_f32_16x16x32_bf16(xsf[ti], btf[tj], accst[ti][tj], 0, 0, 0);
        }
    }
    float dtot = Aexp[63];
    #pragma unroll
    for (int ti = 0; ti < 2; ti++)
      #pragma unroll
      for (int tj = 0; tj < 2; tj++) {
        int nn = qj + tj * 16 + lr;
        #pragma unroll
        for (int r2 = 0; r2 < 4; r2++) {
          int pp = qi + ti * 16 + lg + r2;
          int idx = pp * 64 + nn;
          S[idx] = dtot * S[idx] + accst[ti][tj][r2];
        }
      }
    #pragma unroll
    for (int ti = 0; ti < 2; ti++)
      #pragma unroll
      for (int tj = 0; tj < 2; tj++) {
        int pcol = qj + tj * 16 + lr;
        int d = h * 64 + pcol;
        float dsk = Dskip[d];
        #pragma unroll
        for (int r2 = 0; r2 < 4; r2++) {
          int lrow = qi + ti * 16 + lg + r2;
          size_t bl = (size_t)bl0 + lrow;
          float y = accy[ti][tj][r2];
          float xa = bf2f(xg[bl * 4096 + d]);
          float z = bf2f(proj[bl * 8448 + 4096 + d]);
          float sz = z / (1.f + __expf(-z));
          Yout[bl * 4096 + d] = f2bf((y + dsk * xa) * sz);
        }
      }
  }
}

// ---------------- launch ----------------
extern "C" void kernel_launch(void* const* d_in, const int* in_sizes, int n_in,
                              void* d_out, int out_size, void* d_ws, size_t ws_size,
                              hipStream_t stream) {
  const float* x    = (const float*)d_in[0];
  const float* w1   = (const float*)d_in[1];
  const float* cw   = (const float*)d_in[2];
  const float* cbv  = (const float*)d_in[3];
  const float* w2   = (const float*)d_in[4];
  const float* alog = (const float*)d_in[5];
  const float* dsk  = (const float*)d_in[6];
  const float* dtb  = (const float*)d_in[7];
  float* out = (float*)d_out;

  char* ws = (char*)d_ws;
  u16*  x_bf  = (u16*)(ws + 0);            // 16.8 MB
  u16*  w1p   = (u16*)(ws + 16777216);     // 34.6 MB
  u16*  w2b   = (u16*)(ws + 51380224);     // 16.8 MB
  u16*  proj  = (u16*)(ws + 68157440);     // 69.2 MB
  float* dtf  = (float*)(ws + 137363456);  // 1 MB
  u16*  Bbf   = (u16*)(ws + 138412032);    // 0.5 MB
  u16*  Cbf   = (u16*)(ws + 138936320);    // 0.5 MB
  u16*  xact  = (u16*)(ws + 139460608);    // 33.6 MB
  u16*  yin   = (u16*)(ws + 206569472);    // 33.6 MB
  u16*  Stg   = (u16*)(ws + 240123904);    // 33.6 MB
  float* dtot = (float*)(ws + 273678336);  // 16 KB
  const size_t NEED_PAR = 273694720ull;
  // split-K partials overlay proj (free after ssd_y; rewritten by gemm1 each call)
  float* p0 = (float*)(ws + 68157440);     // 33.6 MB
  float* p1 = p0 + 8388608;                // 33.6 MB (fits in proj's 69.2 MB)

  castall<<<33280, 256, 0, stream>>>(x, w1, w2, x_bf, w1p, w2b);

  gemm128<<<2112, 256, 0, stream>>>(x_bf, w1p, proj, 8448, 2048);

  postproj<<<1024, 256, 0, stream>>>(proj, dtb, dtf, Bbf, Cbf);
  conv_silu<<<dim3(1024, 2), 256, 0, stream>>>(proj, cw, cbv, xact);

  if (ws_size >= NEED_PAR) {
    ssd_states<<<4096, 256, 0, stream>>>(xact, Bbf, dtf, alog, Stg, dtot);
    ssd_scan<<<2048, 256, 0, stream>>>(Stg, dtot);
    ssd_y<<<4096, 256, 0, stream>>>(xact, Bbf, Cbf, dtf, alog, proj, dsk, Stg, yin);
  } else {
    ssd_kernel<<<128, 256, 0, stream>>>(xact, Bbf, Cbf, dtf, alog, proj, dsk, yin);
  }

  gemm128sk<<<1024, 256, 0, stream>>>(yin, w2b, p0, 2048, 2048, 4096);
  addp<<<8192, 256, 0, stream>>>(p0, p1, out);
}

// Round 14
// 384.637 us; speedup vs baseline: 1.0347x; 1.0347x over previous
//
#include <hip/hip_runtime.h>

typedef unsigned short u16;
typedef unsigned int   u32;
typedef __attribute__((ext_vector_type(8))) short bf16x8;
typedef __attribute__((ext_vector_type(4))) float f32x4;

__device__ __forceinline__ u16 f2bf(float f){
  u32 u = __builtin_bit_cast(u32, f);
  u32 r = (u + 0x7FFFu + ((u >> 16) & 1u)) >> 16;
  return (u16)r;
}
__device__ __forceinline__ float bf2f(u16 h){
  u32 u = ((u32)h) << 16;
  return __builtin_bit_cast(float, u);
}
__device__ __forceinline__ void llds16(const u16* g, u16* l){
  __builtin_amdgcn_global_load_lds((const __attribute__((address_space(1))) void*)g,
                                   (__attribute__((address_space(3))) void*)l, 16, 0, 0);
}

#define FENCE asm volatile("" ::: "memory")
#define BAR   do { FENCE; __builtin_amdgcn_s_barrier(); FENCE; } while (0)
#define LGKM0 do { asm volatile("s_waitcnt lgkmcnt(0)" ::: "memory"); __builtin_amdgcn_sched_barrier(0); } while (0)
#define VMC6  do { asm volatile("s_waitcnt vmcnt(6)" ::: "memory"); __builtin_amdgcn_sched_barrier(0); } while (0)
#define VMC0  do { asm volatile("s_waitcnt vmcnt(0)" ::: "memory"); __builtin_amdgcn_sched_barrier(0); } while (0)

#define MFMAQ(mh, nh)                                                         \
  _Pragma("unroll") for (int i = 0; i < 4; i++)                               \
    _Pragma("unroll") for (int j = 0; j < 2; j++)                             \
      _Pragma("unroll") for (int kb = 0; kb < 2; kb++)                        \
        acc[mh][nh][i][j] = __builtin_amdgcn_mfma_f32_16x16x32_bf16(          \
            a[i][kb], bfr[j][kb], acc[mh][nh][i][j], 0, 0, 0);

// ---------------- fused casts: x (2.1M f4) | w1 pad (4.3M f4) | w2 (2.1M f4) ----------------
__global__ __launch_bounds__(256)
void castall(const float* __restrict__ x, const float* __restrict__ w1, const float* __restrict__ w2,
             u16* __restrict__ x_bf, u16* __restrict__ w1p, u16* __restrict__ w2b)
{
  int i = blockIdx.x * 256 + threadIdx.x;    // over 8,519,680 float4
  float4 v;
  uint2* dst;
  if (i < 2097152) {
    v = ((const float4*)x)[i];
    dst = (uint2*)x_bf + i;
  } else if (i < 2097152 + 4325376) {
    int j = i - 2097152;                     // float4 index over 8448*512
    int nrow = j >> 9;
    v = make_float4(0.f, 0.f, 0.f, 0.f);
    if (nrow < 8384) v = ((const float4*)w1)[j];
    dst = (uint2*)w1p + j;
  } else {
    int j = i - 6422528;
    v = ((const float4*)w2)[j];
    dst = (uint2*)w2b + j;
  }
  u32 lo = (u32)f2bf(v.x) | ((u32)f2bf(v.y) << 16);
  u32 hi = (u32)f2bf(v.z) | ((u32)f2bf(v.w) << 16);
  *dst = make_uint2(lo, hi);
}

// ---------------- 128x128 BK=64 GEMM for GEMM1 (m97 structure + subtile swizzle) ----------------
// Grid 2112 = 32 ty x 66 tx. 2D XCD chunk: 8 XCDs = 4 ty-groups(8) x 2 tx-groups(33);
// ty is the fast index within an XCD -> 8 WGs share one B panel (0.5 MB hot), A-panel
// 4.2 MB/XCD ~ L2-resident across the tx sweep. Bijective: (xcd,w) <-> (ty,tx).
__global__ __launch_bounds__(256)
void gemm128(const u16* __restrict__ A, const u16* __restrict__ Bm, u16* __restrict__ Cout,
             int N, int K)
{
  __shared__ u16 As[8192], Bs[8192];
  const int tid = threadIdx.x;
  const int lane = tid & 63, wave = tid >> 6;
  const int wm = (wave >> 1) * 64, wn = (wave & 1) * 64;
  const int lr = lane & 15, lk8 = (lane >> 4) * 8;
  const int lterm = lr * 32 + (lk8 ^ ((lr & 8) << 1));   // swizzled read offset within subtile
  const int lid = blockIdx.x;
  const int xcd = lid & 7, w = lid >> 3;                  // w in [0,264)
  const int ty = (xcd & 3) * 8 + (w & 7);                 // 4 ty-groups of 8
  const int tx = (xcd >> 2) * 33 + (w >> 3);              // 2 tx-groups of 33
  const size_t bm0 = (size_t)ty * 128;
  const size_t bn0 = (size_t)tx * 128;
  const int cg = (lane & 3) ^ ((lane & 32) ? 2 : 0);      // inverse swizzle on k-chunk
  const int rsub = lane >> 2;
  const int ag0 = (wave >> 1) * 8;
  const int bg0 = (wave & 1) * 8;

  f32x4 acc[4][4] = {};

  for (int k0 = 0; k0 < K; k0 += 64) {
    __syncthreads();                                      // prev-tile reads complete (WAR)
    #pragma unroll
    for (int u = 0; u < 4; u++) {
      const int si = wave * 4 + u;                        // subtile 0..15 across 4 waves
      const int row = (si >> 1) * 16 + rsub;
      const int kc = (si & 1) * 32 + cg * 8;
      llds16(A  + (bm0 + row) * (size_t)K + k0 + kc, As + si * 512 + lane * 8);
      llds16(Bm + (bn0 + row) * (size_t)K + k0 + kc, Bs + si * 512 + lane * 8);
    }
    __syncthreads();                                      // drains vmcnt: tile resident
    #pragma unroll
    for (int kb = 0; kb < 2; kb++) {
      bf16x8 af[4], bfv[4];
      #pragma unroll
      for (int m = 0; m < 4; m++) af[m]  = *(const bf16x8*)&As[(ag0 + m * 2 + kb) * 512 + lterm];
      #pragma unroll
      for (int n = 0; n < 4; n++) bfv[n] = *(const bf16x8*)&Bs[(bg0 + n * 2 + kb) * 512 + lterm];
      #pragma unroll
      for (int m = 0; m < 4; m++)
        #pragma unroll
        for (int n = 0; n < 4; n++)
          acc[m][n] = __builtin_amdgcn_mfma_f32_16x16x32_bf16(af[m], bfv[n], acc[m][n], 0, 0, 0);
    }
  }

  const int lg = (lane >> 4) * 4;
  #pragma unroll
  for (int m = 0; m < 4; m++)
    #pragma unroll
    for (int n = 0; n < 4; n++) {
      size_t col = bn0 + wn + n * 16 + lr;
      #pragma unroll
      for (int j = 0; j < 4; j++) {
        size_t row = bm0 + wm + m * 16 + lg + j;
        Cout[row * N + col] = f2bf(acc[m][n][j]);
      }
    }
}

// ---------------- split-K=2 8-phase GEMM (GEMM2): grid 256, ks = lid>>7, 2D XCD chunk ----------------
__global__ __launch_bounds__(512, 2)
void gemm2sk(const u16* __restrict__ A, const u16* __restrict__ Bm, float* __restrict__ P,
             int NYT, int N, int KLEN, int LDK)
{
  __shared__ u16 L[65536];
  const int tid = threadIdx.x;
  const int lane = tid & 63, wid = tid >> 6;
  const int wr = wid >> 2, wc = wid & 3;
  const int lr = lane & 15, lk8 = (lane >> 4) * 8;
  const int lterm = lr * 32 + (lk8 ^ ((lr & 8) << 1));
  const int lid = blockIdx.x;
  const int ks = lid >> 7;                 // k-slice 0/1
  const int lid2 = lid & 127;
  const int xcd = lid2 & 7, w = lid2 >> 3; // w in [0,16)
  const int ty = (xcd & 3) * 4 + (w & 3);  // 2D chunk: 4x4 tiles per XCD
  const int tx = (xcd >> 2) * 4 + (w >> 2);
  const size_t bm0 = (size_t)ty * 256;
  const size_t bn0 = (size_t)tx * 256;
  const int NT = KLEN >> 6;
  const size_t koff = (size_t)ks * KLEN;
  float* Pout = P + (size_t)ks * 8388608;  // 4096*2048

  const int si0 = wid * 2, si1 = si0 + 1;
  const int rsub = lane >> 2;
  const int cg = (lane & 3) ^ ((lane & 32) ? 2 : 0);
  const int rh0 = (si0 >> 1) * 16 + rsub, kc0 = (si0 & 1) * 32 + cg * 8;
  const int rh1 = (si1 >> 1) * 16 + rsub, kc1 = (si1 & 1) * 32 + cg * 8;

  auto stage = [&](int isA, int h, int tt) {
    const int slot = (tt & 1) * 4 + (isA ? 0 : 2) + h;
    const u16* gb = (isA ? A : Bm) + ((isA ? bm0 : bn0) + (size_t)h * 128) * (size_t)LDK + koff;
    u16* lb = L + slot * 8192 + lane * 8;
    llds16(gb + (size_t)rh0 * LDK + (size_t)tt * 64 + kc0, lb + si0 * 512);
    llds16(gb + (size_t)rh1 * LDK + (size_t)tt * 64 + kc1, lb + si1 * 512);
  };

  bf16x8 a[4][2], bfr[2][2];
  f32x4 acc[2][2][4][2] = {};

  auto rdA = [&](int p, int mh) {
    #pragma unroll
    for (int i = 0; i < 4; i++)
      #pragma unroll
      for (int kb = 0; kb < 2; kb++)
        a[i][kb] = *(const bf16x8*)&L[(p * 4 + mh) * 8192 + ((wr * 4 + i) * 2 + kb) * 512 + lterm];
  };
  auto rdB = [&](int p, int nh) {
    #pragma unroll
    for (int j = 0; j < 2; j++)
      #pragma unroll
      for (int kb = 0; kb < 2; kb++)
        bfr[j][kb] = *(const bf16x8*)&L[(p * 4 + 2 + nh) * 8192 + ((wc * 2 + j) * 2 + kb) * 512 + lterm];
  };

  stage(1, 0, 0); stage(1, 1, 0); stage(0, 0, 0); stage(0, 1, 0);
  stage(1, 0, 1); stage(1, 1, 1); stage(0, 0, 1);
  VMC6;
  BAR;

  for (int t = 0; t < NT; ++t) {
    const int p = t & 1;
    const bool s1 = (t + 1 < NT);
    const bool s2 = (t + 2 < NT);
    rdA(p, 0); rdB(p, 0);
    if (s1) stage(0, 1, t + 1);
    BAR; LGKM0;
    __builtin_amdgcn_s_setprio(1); MFMAQ(0, 0); __builtin_amdgcn_s_setprio(0);
    BAR;
    rdB(p, 1);
    if (s2) stage(1, 0, t + 2);
    BAR; LGKM0;
    __builtin_amdgcn_s_setprio(1); MFMAQ(0, 1); __builtin_amdgcn_s_setprio(0);
    BAR;
    rdA(p, 1); rdB(p, 0);
    BAR; LGKM0;
    __builtin_amdgcn_s_setprio(1); MFMAQ(1, 0); __builtin_amdgcn_s_setprio(0);
    BAR;
    rdB(p, 1);
    if (s2) { stage(1, 1, t + 2); stage(0, 0, t + 2); }
    if (t < NT - 2) { VMC6; } else { VMC0; }
    BAR; LGKM0;
    __builtin_amdgcn_s_setprio(1); MFMAQ(1, 1); __builtin_amdgcn_s_setprio(0);
    BAR;
  }

  const int lg4 = (lane >> 4) * 4;
  #pragma unroll
  for (int mh = 0; mh < 2; mh++)
    #pragma unroll
    for (int nh = 0; nh < 2; nh++)
      #pragma unroll
      for (int i = 0; i < 4; i++)
        #pragma unroll
        for (int j = 0; j < 2; j++) {
          size_t col = bn0 + nh * 128 + wc * 32 + j * 16 + lr;
          #pragma unroll
          for (int r2 = 0; r2 < 4; r2++) {
            size_t row = bm0 + mh * 128 + wr * 64 + i * 16 + lg4 + r2;
            Pout[row * N + col] = acc[mh][nh][i][j][r2];
          }
        }
}

// ---------------- partial add: out = p0 + p1 (f32, float4) ----------------
__global__ __launch_bounds__(256)
void addp(const float* __restrict__ p0, const float* __restrict__ p1, float* __restrict__ out){
  int i = blockIdx.x * 256 + threadIdx.x;   // over 2097152 float4
  float4 a = ((const float4*)p0)[i];
  float4 b = ((const float4*)p1)[i];
  ((float4*)out)[i] = make_float4(a.x + b.x, a.y + b.y, a.z + b.z, a.w + b.w);
}

// ---------------- postproj: dt_f, B, C ----------------
__global__ __launch_bounds__(256)
void postproj(const u16* __restrict__ proj, const float* __restrict__ dt_bias,
              float* __restrict__ dtf, u16* __restrict__ Bb, u16* __restrict__ Cb)
{
  int i = blockIdx.x * 256 + threadIdx.x;     // over 4096*64
  if (i >= 4096 * 64) return;
  int bl = i >> 6, hh = i & 63;
  const u16* pr = proj + (size_t)bl * 8448;
  float dv = bf2f(pr[8320 + hh]) + dt_bias[hh];
  dtf[i] = dv > 20.f ? dv : log1pf(__expf(dv));
  Bb[i] = pr[8192 + hh];
  Cb[i] = pr[8256 + hh];
}

// ---------------- conv + silu: writes ONLY xact ----------------
__global__ __launch_bounds__(256)
void conv_silu(const u16* __restrict__ proj, const float* __restrict__ cw,
               const float* __restrict__ cb, u16* __restrict__ xact)
{
  const int g = blockIdx.x;                  // 0..1023, 4 consecutive bl each (batch-aligned)
  const int bl0 = g * 4;
  const int l0 = bl0 & 2047;
  const int d0 = blockIdx.y * 2048 + threadIdx.x * 8;
  float4 wv[8];
  #pragma unroll
  for (int e = 0; e < 8; e++) wv[e] = *(const float4*)&cw[(size_t)(d0 + e) * 4];
  float bias[8];
  {
    float4 b0 = *(const float4*)&cb[d0];
    float4 b1 = *(const float4*)&cb[d0 + 4];
    bias[0]=b0.x; bias[1]=b0.y; bias[2]=b0.z; bias[3]=b0.w;
    bias[4]=b1.x; bias[5]=b1.y; bias[6]=b1.z; bias[7]=b1.w;
  }
  float r[7][8];
  #pragma unroll
  for (int t = 0; t < 7; t++) {
    const int l = l0 - 3 + t;
    if (l >= 0) {
      uint4 rv = *(const uint4*)(proj + (size_t)(bl0 - 3 + t) * 8448 + d0);
      const u16* re = (const u16*)&rv;
      #pragma unroll
      for (int e = 0; e < 8; e++) r[t][e] = bf2f(re[e]);
    } else {
      #pragma unroll
      for (int e = 0; e < 8; e++) r[t][e] = 0.f;
    }
  }
  #pragma unroll
  for (int lo = 0; lo < 4; lo++) {
    u16 xo[8];
    #pragma unroll
    for (int e = 0; e < 8; e++) {
      float v = bias[e] + wv[e].x * r[lo][e] + wv[e].y * r[lo + 1][e]
                        + wv[e].z * r[lo + 2][e] + wv[e].w * r[lo + 3][e];
      float sil = v / (1.f + __expf(-v));
      xo[e]  = f2bf(sil);
    }
    *(uint4*)(xact + (size_t)(bl0 + lo) * 4096 + d0) = *(const uint4*)xo;
  }
}

// ---------------- SSD pass 1: per-(b,c,h) chunk states -> Stg (bf16), dtot ----------------
__global__ __launch_bounds__(256)
void ssd_states(const u16* __restrict__ xg, const u16* __restrict__ Bg,
                const float* __restrict__ dtf, const float* __restrict__ A_log,
                u16* __restrict__ Stg, float* __restrict__ dtot)
{
  const int wg = blockIdx.x;                 // b*2048 + c*64 + h
  const int b = wg >> 11, h = wg & 63;
  const int c = (wg >> 6) & 31;
  const int bl0 = b * 2048 + c * 64;
  __shared__ u16 Bt[64*64], Xts[64*64];
  __shared__ float avals[64], Acum[64], Adec[64];
  const int tid = threadIdx.x, wave = tid >> 6, lane = tid & 63;
  const int qi = (wave >> 1) * 32, qj = (wave & 1) * 32;
  const int lr = lane & 15, lk8 = (lane >> 4) * 8, lg = (lane >> 4) * 4;
  const float negA = -__expf(A_log[h]);

  if (tid < 64) avals[tid] = negA * dtf[(size_t)(bl0 + tid) * 64 + h];
  __syncthreads();
  if (tid < 64) { float s = 0.f; for (int j = 0; j <= tid; j++) s += avals[j]; Acum[tid] = s; }
  __syncthreads();
  if (tid < 64) Adec[tid] = __expf(Acum[63] - Acum[tid]);
  if (tid == 0) dtot[wg] = __expf(Acum[63]);
  __syncthreads();
  {
    int s = tid & 63, c0 = (tid >> 6) * 16;
    float f = dtf[(size_t)(bl0 + s) * 64 + h] * Adec[s];
    const u16* bs = Bg + (size_t)(bl0 + s) * 64 + c0;
    const u16* xs = xg + (size_t)(bl0 + s) * 4096 + h * 64 + c0;
    #pragma unroll
    for (int j = 0; j < 16; j++) {
      Bt[(c0 + j) * 64 + s] = bs[j];
      Xts[(c0 + j) * 64 + s] = f2bf(bf2f(xs[j]) * f);
    }
  }
  __syncthreads();
  f32x4 accst[2][2] = {};
  #pragma unroll
  for (int kk = 0; kk < 64; kk += 32) {
    bf16x8 xsf[2], btf[2];
    #pragma unroll
    for (int t = 0; t < 2; t++) {
      xsf[t] = *(const bf16x8*)&Xts[(qi + t * 16 + lr) * 64 + kk + lk8];
      btf[t] = *(const bf16x8*)&Bt [(qj + t * 16 + lr) * 64 + kk + lk8];
    }
    #pragma unroll
    for (int ti = 0; ti < 2; ti++)
      #pragma unroll
      for (int tj = 0; tj < 2; tj++)
        accst[ti][tj] = __builtin_amdgcn_mfma_f32_16x16x32_bf16(xsf[ti], btf[tj], accst[ti][tj], 0, 0, 0);
  }
  u16* So = Stg + (size_t)wg * 4096;
  #pragma unroll
  for (int ti = 0; ti < 2; ti++)
    #pragma unroll
    for (int tj = 0; tj < 2; tj++) {
      int nn = qj + tj * 16 + lr;
      #pragma unroll
      for (int r2 = 0; r2 < 4; r2++) {
        int pp = qi + ti * 16 + lg + r2;
        So[pp * 64 + nn] = f2bf(accst[ti][tj][r2]);
      }
    }
}

// ---------------- SSD pass 2: in-place scan over chunks ----------------
__global__ __launch_bounds__(256)
void ssd_scan(u16* __restrict__ Stg, const float* __restrict__ dtot)
{
  const int gid = blockIdx.x * 256 + threadIdx.x;  // 524288 threads
  const int bh = gid >> 12;                        // (b,h): 0..127
  const int pn = gid & 4095;
  const int b = bh >> 6, h = bh & 63;
  float R = 0.f;
  for (int c = 0; c < 32; ++c) {
    const int whc = b * 2048 + c * 64 + h;
    size_t idx = (size_t)whc * 4096 + pn;
    float st = bf2f(Stg[idx]);
    Stg[idx] = f2bf(R);                            // S_prev for chunk c
    R = R * dtot[whc] + st;
  }
}

// ---------------- SSD pass 3: per-(b,c,h) Y = Ydiag + Yoff, epilogue ----------------
__global__ __launch_bounds__(256)
void ssd_y(const u16* __restrict__ xg, const u16* __restrict__ Bg, const u16* __restrict__ Cg,
           const float* __restrict__ dtf, const float* __restrict__ A_log,
           const u16* __restrict__ proj, const float* __restrict__ Dskip,
           const u16* __restrict__ Stg, u16* __restrict__ Yout)
{
  const int wg = blockIdx.x;
  const int b = wg >> 11, h = wg & 63;
  const int c = (wg >> 6) & 31;
  const int bl0 = b * 2048 + c * 64;
  __shared__ u16 Cb[64*64], Bb[64*64], Xt[64*64], Sb[64*64], P[64*64];
  __shared__ float avals[64], Acum[64], Aexp[64];
  const int tid = threadIdx.x, wave = tid >> 6, lane = tid & 63;
  const int qi = (wave >> 1) * 32, qj = (wave & 1) * 32;
  const int lr = lane & 15, lk8 = (lane >> 4) * 8, lg = (lane >> 4) * 4;
  const float negA = -__expf(A_log[h]);

  if (tid < 64) avals[tid] = negA * dtf[(size_t)(bl0 + tid) * 64 + h];
  __syncthreads();
  if (tid < 64) { float s = 0.f; for (int j = 0; j <= tid; j++) s += avals[j]; Acum[tid] = s; }
  __syncthreads();
  if (tid < 64) Aexp[tid] = __expf(Acum[tid]);
  __syncthreads();
  {
    int l = tid >> 2, n0 = (tid & 3) * 16;
    const uint4* s0 = (const uint4*)(Cg + (size_t)(bl0 + l) * 64 + n0);
    *(uint4*)&Cb[l * 64 + n0] = s0[0]; *(uint4*)&Cb[l * 64 + n0 + 8] = s0[1];
    const uint4* s1 = (const uint4*)(Bg + (size_t)(bl0 + l) * 64 + n0);
    *(uint4*)&Bb[l * 64 + n0] = s1[0]; *(uint4*)&Bb[l * 64 + n0 + 8] = s1[1];
    int s = tid & 63, c0 = (tid >> 6) * 16;
    float dts = dtf[(size_t)(bl0 + s) * 64 + h];
    const u16* xs = xg + (size_t)(bl0 + s) * 4096 + h * 64 + c0;
    #pragma unroll
    for (int j = 0; j < 16; j++) Xt[(c0 + j) * 64 + s] = f2bf(bf2f(xs[j]) * dts);
    const uint4* sp = (const uint4*)(Stg + (size_t)wg * 4096 + tid * 16);
    *(uint4*)&Sb[tid * 16] = sp[0]; *(uint4*)&Sb[tid * 16 + 8] = sp[1];
  }
  __syncthreads();
  f32x4 accs[2][2] = {}; f32x4 accy[2][2] = {};
  #pragma unroll
  for (int kk = 0; kk < 64; kk += 32) {
    bf16x8 cf[2], bfr[2], sf[2];
    #pragma unroll
    for (int t = 0; t < 2; t++) {
      cf[t]  = *(const bf16x8*)&Cb[(qi + t * 16 + lr) * 64 + kk + lk8];
      bfr[t] = *(const bf16x8*)&Bb[(qj + t * 16 + lr) * 64 + kk + lk8];
      sf[t]  = *(const bf16x8*)&Sb[(qj + t * 16 + lr) * 64 + kk + lk8];
    }
    #pragma unroll
    for (int ti = 0; ti < 2; ti++)
      #pragma unroll
      for (int tj = 0; tj < 2; tj++) {
        accs[ti][tj] = __builtin_amdgcn_mfma_f32_16x16x32_bf16(cf[ti], bfr[tj], accs[ti][tj], 0, 0, 0);
        accy[ti][tj] = __builtin_amdgcn_mfma_f32_16x16x32_bf16(cf[ti], sf[tj],  accy[ti][tj], 0, 0, 0);
      }
  }
  #pragma unroll
  for (int ti = 0; ti < 2; ti++)
    #pragma unroll
    for (int tj = 0; tj < 2; tj++) {
      int j = qj + tj * 16 + lr;
      float Aj = Acum[j];
      #pragma unroll
      for (int r2 = 0; r2 < 4; r2++) {
        int i = qi + ti * 16 + lg + r2;
        float v = (i >= j) ? accs[ti][tj][r2] * __expf(Acum[i] - Aj) : 0.f;
        P[i * 64 + j] = f2bf(v);
        accy[ti][tj][r2] *= Aexp[i];
      }
    }
  __syncthreads();
  #pragma unroll
  for (int kk = 0; kk < 64; kk += 32) {
    bf16x8 pf[2], xf_[2];
    #pragma unroll
    for (int t = 0; t < 2; t++) {
      pf[t]  = *(const bf16x8*)&P [(qi + t * 16 + lr) * 64 + kk + lk8];
      xf_[t] = *(const bf16x8*)&Xt[(qj + t * 16 + lr) * 64 + kk + lk8];
    }
    #pragma unroll
    for (int ti = 0; ti < 2; ti++)
      #pragma unroll
      for (int tj = 0; tj < 2; tj++)
        accy[ti][tj] = __builtin_amdgcn_mfma_f32_16x16x32_bf16(pf[ti], xf_[tj], accy[ti][tj], 0, 0, 0);
  }
  #pragma unroll
  for (int ti = 0; ti < 2; ti++)
    #pragma unroll
    for (int tj = 0; tj < 2; tj++) {
      int pcol = qj + tj * 16 + lr;
      int d = h * 64 + pcol;
      float dsk = Dskip[d];
      #pragma unroll
      for (int r2 = 0; r2 < 4; r2++) {
        int lrow = qi + ti * 16 + lg + r2;
        size_t bl = (size_t)bl0 + lrow;
        float y = accy[ti][tj][r2];
        float xa = bf2f(xg[bl * 4096 + d]);
        float z = bf2f(proj[bl * 8448 + 4096 + d]);
        float sz = z / (1.f + __expf(-z));
        Yout[bl * 4096 + d] = f2bf((y + dsk * xa) * sz);
      }
    }
}

// ---------------- SSD fallback: one WG per (b,h), sequential ----------------
__global__ __launch_bounds__(256)
void ssd_kernel(const u16* __restrict__ xg, const u16* __restrict__ Bg, const u16* __restrict__ Cg,
                const float* __restrict__ dtf, const float* __restrict__ A_log,
                const u16* __restrict__ proj, const float* __restrict__ Dskip,
                u16* __restrict__ Yout)
{
  const int bh = blockIdx.x;
  const int b = bh >> 6, h = bh & 63;
  __shared__ float S[64 * 64];
  __shared__ u16 Cb[64*64], Bb[64*64], Bt[64*64], Xt[64*64], Xts[64*64], Sb[64*64], P[64*64];
  __shared__ float avals[64], Acum[64], Adec[64], Aexp[64];
  const int tid = threadIdx.x, wave = tid >> 6, lane = tid & 63;
  const int qi = (wave >> 1) * 32, qj = (wave & 1) * 32;
  const int lr = lane & 15, lk8 = (lane >> 4) * 8, lg = (lane >> 4) * 4;
  const float negA = -__expf(A_log[h]);

  for (int i = tid; i < 4096; i += 256) S[i] = 0.f;

  for (int c = 0; c < 32; ++c) {
    const int bl0 = b * 2048 + c * 64;
    __syncthreads();
    if (tid < 64) avals[tid] = negA * dtf[(size_t)(bl0 + tid) * 64 + h];
    __syncthreads();
    if (tid < 64) { float s = 0.f; for (int j = 0; j <= tid; j++) s += avals[j]; Acum[tid] = s; }
    __syncthreads();
    if (tid < 64) { float At = Acum[63]; Adec[tid] = __expf(At - Acum[tid]); Aexp[tid] = __expf(Acum[tid]); }
    __syncthreads();
    {
      int l = tid >> 2, n0 = (tid & 3) * 16;
      const uint4* s0 = (const uint4*)(Cg + (size_t)(bl0 + l) * 64 + n0);
      *(uint4*)&Cb[l * 64 + n0] = s0[0]; *(uint4*)&Cb[l * 64 + n0 + 8] = s0[1];
      const uint4* s1 = (const uint4*)(Bg + (size_t)(bl0 + l) * 64 + n0);
      *(uint4*)&Bb[l * 64 + n0] = s1[0]; *(uint4*)&Bb[l * 64 + n0 + 8] = s1[1];
      int s = tid & 63, c0 = (tid >> 6) * 16;
      float dec = Adec[s];
      float dts = dtf[(size_t)(bl0 + s) * 64 + h];
      const u16* bs = Bg + (size_t)(bl0 + s) * 64 + c0;
      const u16* xs = xg + (size_t)(bl0 + s) * 4096 + h * 64 + c0;
      #pragma unroll
      for (int j = 0; j < 16; j++) {
        Bt[(c0 + j) * 64 + s] = bs[j];
        float xv = bf2f(xs[j]) * dts;
        Xt[(c0 + j) * 64 + s] = f2bf(xv);
        Xts[(c0 + j) * 64 + s] = f2bf(xv * dec);
      }
      int p = tid >> 2, m0 = (tid & 3) * 16;
      #pragma unroll
      for (int j = 0; j < 16; j++) Sb[p * 64 + m0 + j] = f2bf(S[p * 64 + m0 + j]);
    }
    __syncthreads();
    f32x4 accs[2][2] = {}; f32x4 accy[2][2] = {};
    #pragma unroll
    for (int kk = 0; kk < 64; kk += 32) {
      bf16x8 cf[2], bfr[2], sf[2];
      #pragma unroll
      for (int t = 0; t < 2; t++) {
        cf[t]  = *(const bf16x8*)&Cb[(qi + t * 16 + lr) * 64 + kk + lk8];
        bfr[t] = *(const bf16x8*)&Bb[(qj + t * 16 + lr) * 64 + kk + lk8];
        sf[t]  = *(const bf16x8*)&Sb[(qj + t * 16 + lr) * 64 + kk + lk8];
      }
      #pragma unroll
      for (int ti = 0; ti < 2; ti++)
        #pragma unroll
        for (int tj = 0; tj < 2; tj++) {
          accs[ti][tj] = __builtin_amdgcn_mfma_f32_16x16x32_bf16(cf[ti], bfr[tj], accs[ti][tj], 0, 0, 0);
          accy[ti][tj] = __builtin_amdgcn_mfma_f32_16x16x32_bf16(cf[ti], sf[tj],  accy[ti][tj], 0, 0, 0);
        }
    }
    #pragma unroll
    for (int ti = 0; ti < 2; ti++)
      #pragma unroll
      for (int tj = 0; tj < 2; tj++) {
        int j = qj + tj * 16 + lr;
        float Aj = Acum[j];
        #pragma unroll
        for (int r2 = 0; r2 < 4; r2++) {
          int i = qi + ti * 16 + lg + r2;
          float v = (i >= j) ? accs[ti][tj][r2] * __expf(Acum[i] - Aj) : 0.f;
          P[i * 64 + j] = f2bf(v);
          accy[ti][tj][r2] *= Aexp[i];
        }
      }
    __syncthreads();
    f32x4 accst[2][2] = {};
    #pragma unroll
    for (int kk = 0; kk < 64; kk += 32) {
      bf16x8 pf[2], xf_[2], xsf[2], btf[2];
      #pragma unroll
      for (int t = 0; t < 2; t++) {
        pf[t]  = *(const bf16x8*)&P  [(qi + t * 16 + lr) * 64 + kk + lk8];
        xf_[t] = *(const bf16x8*)&Xt [(qj + t * 16 + lr) * 64 + kk + lk8];
        xsf[t] = *(const bf16x8*)&Xts[(qi + t * 16 + lr) * 64 + kk + lk8];
        btf[t] = *(const bf16x8*)&Bt [(qj + t * 16 + lr) * 64 + kk + lk8];
      }
      #pragma unroll
      for (int ti = 0; ti < 2; ti++)
        #pragma unroll
        for (int tj = 0; tj < 2; tj++) {
          accy[ti][tj]  = __builtin_amdgcn_mfma_f32_16x16x32_bf16(pf[ti],  xf_[tj], accy[ti][tj],  0, 0, 0);
          accst[ti][tj] = __builtin_amdgcn_mfma_f32_16x16x32_bf16(xsf[ti], btf[tj], accst[ti][tj], 0, 0, 0);
        }
    }
    float dtot = Aexp[63];
    #pragma unroll
    for (int ti = 0; ti < 2; ti++)
      #pragma unroll
      for (int tj = 0; tj < 2; tj++) {
        int nn = qj + tj * 16 + lr;
        #pragma unroll
        for (int r2 = 0; r2 < 4; r2++) {
          int pp = qi + ti * 16 + lg + r2;
          int idx = pp * 64 + nn;
          S[idx] = dtot * S[idx] + accst[ti][tj][r2];
        }
      }
    #pragma unroll
    for (int ti = 0; ti < 2; ti++)
      #pragma unroll
      for (int tj = 0; tj < 2; tj++) {
        int pcol = qj + tj * 16 + lr;
        int d = h * 64 + pcol;
        float dsk = Dskip[d];
        #pragma unroll
        for (int r2 = 0; r2 < 4; r2++) {
          int lrow = qi + ti * 16 + lg + r2;
          size_t bl = (size_t)bl0 + lrow;
          float y = accy[ti][tj][r2];
          float xa = bf2f(xg[bl * 4096 + d]);
          float z = bf2f(proj[bl * 8448 + 4096 + d]);
          float sz = z / (1.f + __expf(-z));
          Yout[bl * 4096 + d] = f2bf((y + dsk * xa) * sz);
        }
      }
  }
}

// ---------------- launch ----------------
extern "C" void kernel_launch(void* const* d_in, const int* in_sizes, int n_in,
                              void* d_out, int out_size, void* d_ws, size_t ws_size,
                              hipStream_t stream) {
  const float* x    = (const float*)d_in[0];
  const float* w1   = (const float*)d_in[1];
  const float* cw   = (const float*)d_in[2];
  const float* cbv  = (const float*)d_in[3];
  const float* w2   = (const float*)d_in[4];
  const float* alog = (const float*)d_in[5];
  const float* dsk  = (const float*)d_in[6];
  const float* dtb  = (const float*)d_in[7];
  float* out = (float*)d_out;

  char* ws = (char*)d_ws;
  u16*  x_bf  = (u16*)(ws + 0);            // 16.8 MB
  u16*  w1p   = (u16*)(ws + 16777216);     // 34.6 MB
  u16*  w2b   = (u16*)(ws + 51380224);     // 16.8 MB
  u16*  proj  = (u16*)(ws + 68157440);     // 69.2 MB
  float* dtf  = (float*)(ws + 137363456);  // 1 MB
  u16*  Bbf   = (u16*)(ws + 138412032);    // 0.5 MB
  u16*  Cbf   = (u16*)(ws + 138936320);    // 0.5 MB
  u16*  xact  = (u16*)(ws + 139460608);    // 33.6 MB
  u16*  yin   = (u16*)(ws + 206569472);    // 33.6 MB
  u16*  Stg   = (u16*)(ws + 240123904);    // 33.6 MB
  float* dtot = (float*)(ws + 273678336);  // 16 KB
  const size_t NEED_PAR = 273694720ull;
  // split-K partials overlay proj (free after ssd_y; rewritten by gemm1 each call)
  float* p0 = (float*)(ws + 68157440);     // 33.6 MB
  float* p1 = p0 + 8388608;                // 33.6 MB (fits in proj's 69.2 MB)

  castall<<<33280, 256, 0, stream>>>(x, w1, w2, x_bf, w1p, w2b);

  gemm128<<<2112, 256, 0, stream>>>(x_bf, w1p, proj, 8448, 2048);

  postproj<<<1024, 256, 0, stream>>>(proj, dtb, dtf, Bbf, Cbf);
  conv_silu<<<dim3(1024, 2), 256, 0, stream>>>(proj, cw, cbv, xact);

  if (ws_size >= NEED_PAR) {
    ssd_states<<<4096, 256, 0, stream>>>(xact, Bbf, dtf, alog, Stg, dtot);
    ssd_scan<<<2048, 256, 0, stream>>>(Stg, dtot);
    ssd_y<<<4096, 256, 0, stream>>>(xact, Bbf, Cbf, dtf, alog, proj, dsk, Stg, yin);
  } else {
    ssd_kernel<<<128, 256, 0, stream>>>(xact, Bbf, Cbf, dtf, alog, proj, dsk, yin);
  }

  gemm2sk<<<256, 512, 0, stream>>>(yin, w2b, p0, 16, 2048, 2048, 4096);
  addp<<<8192, 256, 0, stream>>>(p0, p1, out);
}